// Round 18
// baseline (167.660 us; speedup 1.0000x reference)
//
#include <hip/hip_runtime.h>
#include <math.h>

#define NIN 91392        // 17*21*16*16
#define DIN 8
#define DOUT 16
#define NCHUNK (NIN / 8) // 11424 chunks of 8 n
#define GRID_P 1024      // 4 blocks/CU, 32 waves/CU at <=64 VGPR
#define TPB 512          // 8 waves; wave w owns n-row w of each chunk

typedef float f32x4 __attribute__((ext_vector_type(4)));

// Inline-asm global load, SGPR base + 32-bit voffset + imm. The "=v" output
// forces a real register destination issued immediately; the compiler cannot
// re-serialize these into load->wait->use chains (R9/R11 failure mode:
// VGPR-minimizing allocator kept 1 load in flight). All 12 loads per n issue
// back-to-back; one counted wait covers them; rule #18 sched_barrier pins it.
#define GLB16(dst, voff, base, immstr)                                         \
    asm volatile("global_load_dwordx4 %0, %1, %2 offset:" immstr               \
        : "=v"(dst) : "v"(voff), "s"(base))

// lane=(b0:3)(j:1)(og:2); wave w owns n = c*8+w; thread: batches {b0,b0+8},
// own capsule j, o = og*4..+3. W per instr = 2 cache lines (8x16B shared x8
// lanes); x lines shared across sibling waves (consecutive n). ZERO LDS in
// the main loop -> no DS-pipe wall, no barriers, no DMA protocol.
// PASS 0: s0 partial = sum_n u. PASS>0: c_j = sigmoid(sgn_j*d), 3 shuffles.
template<int PASS>
__global__ __launch_bounds__(TPB) void caps_pass(
    const float* __restrict__ x, const float* __restrict__ W,
    const float* __restrict__ vin, float* __restrict__ part, int grid)
{
    const int t = threadIdx.x;
    const int lane = t & 63;
    const int wave = t >> 6;          // n-row within chunk
    const int og = lane & 3;
    const int j  = (lane >> 2) & 1;
    const int b0 = lane >> 3;         // batches b0, b0+8
    const int bid = blockIdx.x;

    __shared__ float lds2[8 * 576];   // epilogue reduce only (18.4 KB)

    const float sgn = j ? -1.f : 1.f;

    f32x4 vinA = {0.f,0.f,0.f,0.f}, vinB = {0.f,0.f,0.f,0.f};
    if (PASS > 0) {
        vinA = sgn * *(const f32x4*)(vin + b0 * 32 + j * 16 + og * 4);
        vinB = sgn * *(const f32x4*)(vin + (b0 + 8) * 32 + j * 16 + og * 4);
    }

    f32x4 accA = {0.f,0.f,0.f,0.f};
    f32x4 accB = {0.f,0.f,0.f,0.f};

    const int n0 = bid * 8 + wave;
    // byte voffsets (32-bit: W spans 93.6MB, x 46.8MB -- both fit)
    unsigned wvoff = (unsigned)(((size_t)j * NIN + n0) * 512) + og * 16;
    unsigned xvoff = (unsigned)(((size_t)b0 * NIN + n0) * 32);
    const unsigned wstep = (unsigned)grid * 4096;   // grid*8 n * 512 B
    const unsigned xstep = (unsigned)grid * 256;    // grid*8 n * 32 B
    const float* xB = x + (size_t)8 * NIN * 8;      // batch b0+8 base

    for (int c = bid; c < NCHUNK; c += grid) {
        f32x4 W0,W1,W2,W3,W4,W5,W6,W7, XA0,XA1,XB0,XB1;
        // phase 1: W i=0..3 + all x (8 loads in flight)
        GLB16(W0,  wvoff, W,  "0");
        GLB16(W1,  wvoff, W,  "64");
        GLB16(W2,  wvoff, W,  "128");
        GLB16(W3,  wvoff, W,  "192");
        GLB16(XA0, xvoff, x,  "0");
        GLB16(XA1, xvoff, x,  "16");
        GLB16(XB0, xvoff, xB, "0");
        GLB16(XB1, xvoff, xB, "16");
        asm volatile("s_waitcnt vmcnt(0)" ::: "memory");
        __builtin_amdgcn_sched_barrier(0);

        f32x4 u0 = W0 * XA0.x;  u0 += W1 * XA0.y;
        u0 += W2 * XA0.z;       u0 += W3 * XA0.w;
        f32x4 u1 = W0 * XB0.x;  u1 += W1 * XB0.y;
        u1 += W2 * XB0.z;       u1 += W3 * XB0.w;

        // phase 2: W i=4..7 (W0-3 dead -> regs reused)
        GLB16(W4, wvoff, W, "256");
        GLB16(W5, wvoff, W, "320");
        GLB16(W6, wvoff, W, "384");
        GLB16(W7, wvoff, W, "448");
        asm volatile("s_waitcnt vmcnt(0)" ::: "memory");
        __builtin_amdgcn_sched_barrier(0);

        u0 += W4 * XA1.x;  u0 += W5 * XA1.y;
        u0 += W6 * XA1.z;  u0 += W7 * XA1.w;
        u1 += W4 * XB1.x;  u1 += W5 * XB1.y;
        u1 += W6 * XB1.z;  u1 += W7 * XB1.w;

        if (PASS == 0) {
            accA += u0;
            accB += u1;
        } else {
            // d = logit0-logit1: og-reduce (xor 1,2) + j-fold (xor 4), sgn in vin
            float m0 = vinA.x*u0.x + vinA.y*u0.y + vinA.z*u0.z + vinA.w*u0.w;
            float m1 = vinB.x*u1.x + vinB.y*u1.y + vinB.z*u1.z + vinB.w*u1.w;
            m0 += __shfl_xor(m0, 1);  m1 += __shfl_xor(m1, 1);
            m0 += __shfl_xor(m0, 2);  m1 += __shfl_xor(m1, 2);
            m0 += __shfl_xor(m0, 4);  m1 += __shfl_xor(m1, 4);   // = d
            const float cA = __builtin_amdgcn_rcpf(1.f + __expf(-sgn * m0));
            const float cB = __builtin_amdgcn_rcpf(1.f + __expf(-sgn * m1));
            accA += u0 * cA;
            accB += u1 * cB;
        }

        wvoff += wstep;
        xvoff += xstep;
    }

    // ---- epilogue: cross-wave reduce (waves hold disjoint n) ----
    __syncthreads();
    {
        float* sl = lds2 + wave * 576 + lane * 9;
        sl[0]=accA.x; sl[1]=accA.y; sl[2]=accA.z; sl[3]=accA.w;
        sl[4]=accB.x; sl[5]=accB.y; sl[6]=accB.z; sl[7]=accB.w;
    }
    __syncthreads();
    if (t < 64) {
        float s[8];
        #pragma unroll
        for (int q = 0; q < 8; ++q) s[q] = 0.f;
        #pragma unroll
        for (int w = 0; w < 8; ++w) {
            const float* p = lds2 + w * 576 + t * 9;
            #pragma unroll
            for (int q = 0; q < 8; ++q) s[q] += p[q];
        }
        const int tb0 = t >> 3, tj = (t >> 2) & 1, tog = t & 3;
        #pragma unroll
        for (int q = 0; q < 4; ++q) {
            part[(size_t)(tb0*32 + tj*16 + tog*4 + q) * grid + bid] = s[q];
            part[(size_t)((tb0+8)*32 + tj*16 + tog*4 + q) * grid + bid] = s[4+q];
        }
    }
}

// Reduce partials -> s[b,j,o], squash -> v. 32 blocks = one per (b,j).
// PASS 0: scale 0.5 (uniform softmax), write v0
// PASS 1: write v0+v1 (logits linear in accumulated v)
// PASS 2: write final v
template<int PASS>
__global__ __launch_bounds__(256) void caps_reduce(
    const float* __restrict__ part, const float* __restrict__ vprev,
    float* __restrict__ vout, int gridA)
{
    const int blk = blockIdx.x;
    const int b = blk >> 1, j = blk & 1;
    const int t = threadIdx.x;
    const int o = t & 15;
    const int ch = t >> 4;
    const size_t base = ((size_t)b * 32 + j * 16 + o) * gridA;
    float s = 0.f;
    for (int g = ch; g < gridA; g += 16) s += part[base + g];
    __shared__ float red[256];
    red[t] = s;
    __syncthreads();
    if (t < 16) {
        float sv = 0.f;
        #pragma unroll
        for (int c = 0; c < 16; ++c) sv += red[c * 16 + t];
        if (PASS == 0) sv *= 0.5f;
        float sq = sv * sv;
        sq += __shfl_xor(sq, 1);
        sq += __shfl_xor(sq, 2);
        sq += __shfl_xor(sq, 4);
        sq += __shfl_xor(sq, 8);
        const float sn = sq;
        float v = sv * sn / ((1.f + sn) * sqrtf(sn + 1e-7f));
        if (PASS == 1) v += vprev[b * 32 + j * 16 + o];
        vout[b * 32 + j * 16 + o] = v;
    }
}

extern "C" void kernel_launch(void* const* d_in, const int* in_sizes, int n_in,
                              void* d_out, int out_size, void* d_ws, size_t ws_size,
                              hipStream_t stream) {
    const float* x = (const float*)d_in[0];
    const float* W = (const float*)d_in[1];
    float* out = (float*)d_out;

    // grid clamped to workspace (part = 512*GRID floats)
    size_t maxg = (ws_size - 4096) / (512 * sizeof(float));
    int GRID = (int)(maxg < GRID_P ? maxg : GRID_P);
    if (GRID < 1) GRID = 1;

    float* part = (float*)d_ws;                       // 512*GRID floats (2 MB)
    float* v0   = part + (size_t)512 * GRID;          // 512
    float* vsum = v0 + 512;                           // 512

    caps_pass<0><<<GRID, TPB, 0, stream>>>(x, W, nullptr, part, GRID);
    caps_reduce<0><<<32, 256, 0, stream>>>(part, nullptr, v0, GRID);
    caps_pass<1><<<GRID, TPB, 0, stream>>>(x, W, v0, part, GRID);
    caps_reduce<1><<<32, 256, 0, stream>>>(part, v0, vsum, GRID);
    caps_pass<2><<<GRID, TPB, 0, stream>>>(x, W, vsum, part, GRID);
    caps_reduce<2><<<32, 256, 0, stream>>>(part, nullptr, out, GRID);
}